// Round 1
// baseline (1109.464 us; speedup 1.0000x reference)
//
#include <hip/hip_runtime.h>
#include <stdint.h>

// ---------- types / helpers ----------
typedef __attribute__((ext_vector_type(8))) short bf16x8;   // 8 bf16 in 4 VGPRs
typedef __attribute__((ext_vector_type(4))) float f32x4;

static __device__ __forceinline__ short f2bf(float f) {
  uint32_t u = __builtin_bit_cast(uint32_t, f);
  u += 0x7fffu + ((u >> 16) & 1u);          // round-to-nearest-even
  return (short)(u >> 16);
}

static __device__ __forceinline__ void gload_lds16(const void* g, void* l) {
  __builtin_amdgcn_global_load_lds((const __attribute__((address_space(1))) void*)g,
                                   (__attribute__((address_space(3))) void*)l, 16, 0, 0);
}

// ---------- x transpose: (B,C,T,H,W) f32 -> xb[n][c] bf16, n = b*16384 + p ----------
__global__ __launch_bounds__(256) void transpose_x_k(const float* __restrict__ x,
                                                     short* __restrict__ xb) {
  __shared__ float t[64][65];
  const int pt = blockIdx.x, ct = blockIdx.y, b = blockIdx.z;
  const int tid = threadIdx.x;
#pragma unroll
  for (int i = 0; i < 16; i++) {
    int cc = i * 4 + (tid >> 6);
    int pp = tid & 63;
    t[cc][pp] = x[(size_t)(b * 512 + ct * 64 + cc) * 16384 + pt * 64 + pp];
  }
  __syncthreads();
#pragma unroll
  for (int i = 0; i < 2; i++) {
    int seg = i * 256 + tid;
    int pw = seg >> 3, c8 = seg & 7;
    short tmp[8];
#pragma unroll
    for (int k = 0; k < 8; k++) tmp[k] = f2bf(t[c8 * 8 + k][pw]);
    *(uint4*)&xb[(size_t)(b * 16384 + pt * 64 + pw) * 512 + ct * 64 + c8 * 8] =
        *(const uint4*)tmp;
  }
}

// ---------- weight transpose: 12x (512x512 f32 [k][n]) -> bf16 [n][k] ----------
struct WPtrs {
  const float* src[12];
  short* dst[12];
};

__global__ __launch_bounds__(256) void transpose_w_k(WPtrs P) {
  __shared__ float t[64][65];
  const int kt = blockIdx.x, nt = blockIdx.y, z = blockIdx.z;
  const float* src = P.src[z];
  short* dst = P.dst[z];
  const int tid = threadIdx.x;
#pragma unroll
  for (int i = 0; i < 16; i++) {
    int kk = i * 4 + (tid >> 6);
    int nn = tid & 63;
    t[kk][nn] = src[(kt * 64 + kk) * 512 + nt * 64 + nn];
  }
  __syncthreads();
#pragma unroll
  for (int i = 0; i < 2; i++) {
    int seg = i * 256 + tid;
    int nn = seg >> 3, k8 = seg & 7;
    short tmp[8];
#pragma unroll
    for (int k = 0; k < 8; k++) tmp[k] = f2bf(t[k8 * 8 + k][nn]);
    *(uint4*)&dst[(nt * 64 + nn) * 512 + kt * 64 + k8 * 8] = *(const uint4*)tmp;
  }
}

__global__ void bsum_k(const float* a, const float* b, const float* c, float* o) {
  int i = blockIdx.x * 256 + threadIdx.x;
  if (i < 512) o[i] = a[i] + b[i] + c[i];
}

// ---------- GEMM: D = A(MxK) * B(NxK)^T, bf16 inputs, m97 structure ----------
// MODE 0: D is bf16 [M][ldd], write rows=m cols=n
// MODE 1: D is f32 out (B,C,THW): m=c, n=b*16384+p; write + bsum[c]
// MODE 2: same addressing, D += val
#define BM 128
#define BN 128
#define BK 32

template <int MODE>
__global__ __launch_bounds__(256) void gemm_k(const short* __restrict__ A,
                                              const short* __restrict__ B,
                                              void* __restrict__ Dp, int K, int ldd,
                                              const float* __restrict__ bsum) {
  __shared__ short As[BM * BK];
  __shared__ short Bs[BN * BK];
  const int tid = threadIdx.x;
  const int wave = tid >> 6, lane = tid & 63;
  const int bm = blockIdx.x, bn = blockIdx.y;
  const int wm = ((wave >> 1) << 6), wn = ((wave & 1) << 6);
  f32x4 acc[4][4] = {};

  // staging: each wave covers 32 rows (2 insts x 16 rows x 64B)
  const int arow = (wave << 5) + (lane >> 2);
  const int aseg = (lane & 3) << 3;
  const short* gA = A + (size_t)(bm * BM + arow) * K + aseg;
  const short* gB = B + (size_t)(bn * BN + arow) * K + aseg;
  short* lA = &As[(wave << 5) * BK];
  short* lB = &Bs[(wave << 5) * BK];

  const int mrow = lane & 15, koff = (lane >> 4) << 3;

  for (int k0 = 0; k0 < K; k0 += BK) {
    gload_lds16(gA + k0, lA);
    gload_lds16(gA + k0 + 16 * K, lA + 16 * BK);
    gload_lds16(gB + k0, lB);
    gload_lds16(gB + k0 + 16 * K, lB + 16 * BK);
    __syncthreads();
    bf16x8 af[4], bfr[4];
#pragma unroll
    for (int i = 0; i < 4; i++) {
      af[i] = *(const bf16x8*)&As[(wm + i * 16 + mrow) * BK + koff];
      bfr[i] = *(const bf16x8*)&Bs[(wn + i * 16 + mrow) * BK + koff];
    }
#pragma unroll
    for (int mi = 0; mi < 4; mi++)
#pragma unroll
      for (int ni = 0; ni < 4; ni++)
        acc[mi][ni] =
            __builtin_amdgcn_mfma_f32_16x16x32_bf16(af[mi], bfr[ni], acc[mi][ni], 0, 0, 0);
    __syncthreads();
  }

  const int crow0 = (lane >> 4) << 2;
  const int ccol = lane & 15;
  if (MODE == 0) {
    short* D = (short*)Dp;
#pragma unroll
    for (int mi = 0; mi < 4; mi++)
#pragma unroll
      for (int ni = 0; ni < 4; ni++)
#pragma unroll
        for (int r = 0; r < 4; r++) {
          int row = bm * BM + wm + mi * 16 + crow0 + r;
          int col = bn * BN + wn + ni * 16 + ccol;
          D[(size_t)row * ldd + col] = f2bf(acc[mi][ni][r]);
        }
  } else {
    float* D = (float*)Dp;
#pragma unroll
    for (int mi = 0; mi < 4; mi++)
#pragma unroll
      for (int ni = 0; ni < 4; ni++)
#pragma unroll
        for (int r = 0; r < 4; r++) {
          int c = bm * BM + wm + mi * 16 + crow0 + r;     // channel
          int n = bn * BN + wn + ni * 16 + ccol;          // spatial row index
          size_t addr = (size_t)(n >> 14) * 8388608 + (size_t)c * 16384 + (n & 16383);
          float v = acc[mi][ni][r];
          if (MODE == 1)
            D[addr] = v + bsum[c];
          else
            D[addr] += v;
        }
  }
}

// ---------- axial attention: one block per (sequence, head) ----------
// qkv: [n][1536] bf16 (Q|K|V each 512); o: [n][512] bf16
template <int L>
__global__ __launch_bounds__(256) void attn_k(const short* __restrict__ qkv,
                                              short* __restrict__ o, int Adiv, int Bmul,
                                              int Cmul, int stride) {
  constexpr int R = 256 / L;        // threads per row
  constexpr int SPT = (L * L) / 256;  // scores per thread
  constexpr int OPT = 64 / R;       // outputs per thread
  __shared__ short Ks[L][72];
  __shared__ short Vs[L][72];
  __shared__ short Qs[L][72];
  __shared__ float att[L][L + 1];
  const int tid = threadIdx.x;
  const int blk = blockIdx.x;
  const int s = blk >> 3, head = blk & 7;
  const int base = (s / Adiv) * Bmul + (s % Adiv) * Cmul;

  for (int idx = tid; idx < L * 8 * 3; idx += 256) {
    int part = idx / (L * 8);
    int rem = idx - part * (L * 8);
    int row = rem >> 3, seg = rem & 7;
    int n = base + row * stride;
    uint4 v = *(const uint4*)&qkv[(size_t)n * 1536 + part * 512 + head * 64 + seg * 8];
    short* dst = (part == 0 ? &Qs[row][0] : part == 1 ? &Ks[row][0] : &Vs[row][0]);
    *(uint4*)(dst + seg * 8) = v;
  }
  __syncthreads();

  const int l = tid / R, r = tid % R;
  float q[64];
#pragma unroll
  for (int w = 0; w < 8; w++) {
    uint4 u = *(const uint4*)&Qs[l][w * 8];
    uint32_t arr[4] = {u.x, u.y, u.z, u.w};
#pragma unroll
    for (int p = 0; p < 4; p++) {
      q[w * 8 + p * 2] = __builtin_bit_cast(float, arr[p] << 16);
      q[w * 8 + p * 2 + 1] = __builtin_bit_cast(float, arr[p] & 0xffff0000u);
    }
  }
  float sc[SPT];
#pragma unroll
  for (int jj = 0; jj < SPT; jj++) {
    int j = jj * R + r;
    float a0 = 0.f;
#pragma unroll
    for (int w = 0; w < 8; w++) {
      uint4 u = *(const uint4*)&Ks[j][w * 8];
      uint32_t arr[4] = {u.x, u.y, u.z, u.w};
#pragma unroll
      for (int p = 0; p < 4; p++) {
        a0 += q[w * 8 + p * 2] * __builtin_bit_cast(float, arr[p] << 16);
        a0 += q[w * 8 + p * 2 + 1] * __builtin_bit_cast(float, arr[p] & 0xffff0000u);
      }
    }
    sc[jj] = a0 * 0.125f;  // 1/sqrt(64)
  }
  float mx = sc[0];
#pragma unroll
  for (int jj = 1; jj < SPT; jj++) mx = fmaxf(mx, sc[jj]);
#pragma unroll
  for (int d = 1; d < R; d <<= 1) mx = fmaxf(mx, __shfl_xor(mx, d));
  float p_[SPT];
  float sum = 0.f;
#pragma unroll
  for (int jj = 0; jj < SPT; jj++) {
    p_[jj] = __expf(sc[jj] - mx);
    sum += p_[jj];
  }
#pragma unroll
  for (int d = 1; d < R; d <<= 1) sum += __shfl_xor(sum, d);
  float inv = 1.0f / sum;
#pragma unroll
  for (int jj = 0; jj < SPT; jj++) att[l][jj * R + r] = p_[jj] * inv;
  __syncthreads();

  float oa[OPT] = {};
#pragma unroll 4
  for (int j = 0; j < L; j++) {
    float a = att[l][j];
    if constexpr (OPT == 8) {
      uint4 u = *(const uint4*)&Vs[j][r * 8];
      uint32_t arr[4] = {u.x, u.y, u.z, u.w};
#pragma unroll
      for (int p = 0; p < 4; p++) {
        oa[p * 2] += a * __builtin_bit_cast(float, arr[p] << 16);
        oa[p * 2 + 1] += a * __builtin_bit_cast(float, arr[p] & 0xffff0000u);
      }
    } else {
      uint2 u = *(const uint2*)&Vs[j][r * 4];
      uint32_t arr[2] = {u.x, u.y};
#pragma unroll
      for (int p = 0; p < 2; p++) {
        oa[p * 2] += a * __builtin_bit_cast(float, arr[p] << 16);
        oa[p * 2 + 1] += a * __builtin_bit_cast(float, arr[p] & 0xffff0000u);
      }
    }
  }
  short tmp[OPT];
#pragma unroll
  for (int i = 0; i < OPT; i++) tmp[i] = f2bf(oa[i]);
  int n = base + l * stride;
  if constexpr (OPT == 8)
    *(uint4*)&o[(size_t)n * 512 + head * 64 + r * 8] = *(const uint4*)tmp;
  else
    *(uint2*)&o[(size_t)n * 512 + head * 64 + r * 4] = *(const uint2*)tmp;
}

// ---------- launch ----------
extern "C" void kernel_launch(void* const* d_in, const int* in_sizes, int n_in,
                              void* d_out, int out_size, void* d_ws, size_t ws_size,
                              hipStream_t stream) {
  const float* x = (const float*)d_in[0];
  const float* wq[3];
  const float* wk[3];
  const float* wv[3];
  const float* fc[3];
  const float* fb[3];
  for (int a = 0; a < 3; a++) {
    wq[a] = (const float*)d_in[1 + a * 5];
    wk[a] = (const float*)d_in[2 + a * 5];
    wv[a] = (const float*)d_in[3 + a * 5];
    fc[a] = (const float*)d_in[4 + a * 5];
    fb[a] = (const float*)d_in[5 + a * 5];
  }
  char* ws = (char*)d_ws;
  short* xb = (short*)(ws);                      //  67,108,864 B
  short* qkv = (short*)(ws + 67108864);          // 201,326,592 B
  short* ob = (short*)(ws + 268435456);          //  67,108,864 B
  short* wqkvt = (short*)(ws + 335544320);       //   4,718,592 B (3 x 1536x512)
  short* fct = (short*)(ws + 340262912);         //   1,572,864 B (3 x 512x512)
  float* bsum = (float*)(ws + 341835776);        //       2,048 B
  float* out = (float*)d_out;

  WPtrs P;
  for (int a = 0; a < 3; a++) {
    P.src[a * 4 + 0] = wq[a];
    P.src[a * 4 + 1] = wk[a];
    P.src[a * 4 + 2] = wv[a];
    P.src[a * 4 + 3] = fc[a];
    P.dst[a * 4 + 0] = wqkvt + (size_t)a * 1536 * 512;
    P.dst[a * 4 + 1] = wqkvt + (size_t)a * 1536 * 512 + 512 * 512;
    P.dst[a * 4 + 2] = wqkvt + (size_t)a * 1536 * 512 + 2 * 512 * 512;
    P.dst[a * 4 + 3] = fct + (size_t)a * 512 * 512;
  }
  transpose_w_k<<<dim3(8, 8, 12), 256, 0, stream>>>(P);
  bsum_k<<<dim3(2), 256, 0, stream>>>(fb[0], fb[1], fb[2], bsum);
  transpose_x_k<<<dim3(256, 8, 4), 256, 0, stream>>>(x, xb);

  // per-axis attention geometry: base = (s/Adiv)*Bmul + (s%Adiv)*Cmul, rows step `stride`
  const int Ad[3] = {1, 32, 1024};
  const int Bm_[3] = {32, 1024, 16384};
  const int Cm[3] = {0, 1, 1};
  const int St[3] = {1, 32, 1024};
  const int Ls[3] = {32, 32, 16};

  for (int a = 0; a < 3; a++) {
    gemm_k<0><<<dim3(512, 12), 256, 0, stream>>>(xb, wqkvt + (size_t)a * 1536 * 512,
                                                 (void*)qkv, 512, 1536, nullptr);
    if (Ls[a] == 32)
      attn_k<32><<<dim3(2048 * 8), 256, 0, stream>>>(qkv, ob, Ad[a], Bm_[a], Cm[a], St[a]);
    else
      attn_k<16><<<dim3(4096 * 8), 256, 0, stream>>>(qkv, ob, Ad[a], Bm_[a], Cm[a], St[a]);
    if (a == 0)
      gemm_k<1><<<dim3(4, 512), 256, 0, stream>>>(fct + (size_t)a * 512 * 512, ob,
                                                  (void*)out, 512, 0, bsum);
    else
      gemm_k<2><<<dim3(4, 512), 256, 0, stream>>>(fct + (size_t)a * 512 * 512, ob,
                                                  (void*)out, 512, 0, bsum);
  }
}

// Round 3
// 941.033 us; speedup vs baseline: 1.1790x; 1.1790x over previous
//
#include <hip/hip_runtime.h>
#include <stdint.h>

// ---------- types / helpers ----------
typedef __attribute__((ext_vector_type(8))) short bf16x8;   // 8 bf16 in 4 VGPRs
typedef __attribute__((ext_vector_type(4))) float f32x4;

static __device__ __forceinline__ short f2bf(float f) {
  uint32_t u = __builtin_bit_cast(uint32_t, f);
  u += 0x7fffu + ((u >> 16) & 1u);          // round-to-nearest-even
  return (short)(u >> 16);
}

static __device__ __forceinline__ void gload_lds16(const void* g, void* l) {
  __builtin_amdgcn_global_load_lds((const __attribute__((address_space(1))) void*)g,
                                   (__attribute__((address_space(3))) void*)l, 16, 0, 0);
}

#define GFENCE asm volatile("" ::: "memory")

// ---------- x transpose: (B,C,T,H,W) f32 -> xb[n][c] bf16, n = b*16384 + p ----------
__global__ __launch_bounds__(256) void transpose_x_k(const float* __restrict__ x,
                                                     short* __restrict__ xb) {
  __shared__ float t[64][65];
  const int pt = blockIdx.x, ct = blockIdx.y, b = blockIdx.z;
  const int tid = threadIdx.x;
#pragma unroll
  for (int i = 0; i < 16; i++) {
    int cc = i * 4 + (tid >> 6);
    int pp = tid & 63;
    t[cc][pp] = x[(size_t)(b * 512 + ct * 64 + cc) * 16384 + pt * 64 + pp];
  }
  __syncthreads();
#pragma unroll
  for (int i = 0; i < 2; i++) {
    int seg = i * 256 + tid;
    int pw = seg >> 3, c8 = seg & 7;
    short tmp[8];
#pragma unroll
    for (int k = 0; k < 8; k++) tmp[k] = f2bf(t[c8 * 8 + k][pw]);
    *(uint4*)&xb[(size_t)(b * 16384 + pt * 64 + pw) * 512 + ct * 64 + c8 * 8] =
        *(const uint4*)tmp;
  }
}

// ---------- weight transpose: 12x (512x512 f32 [k][n]) -> bf16 [n][k] ----------
struct WPtrs {
  const float* src[12];
  short* dst[12];
};

__global__ __launch_bounds__(256) void transpose_w_k(WPtrs P) {
  __shared__ float t[64][65];
  const int kt = blockIdx.x, nt = blockIdx.y, z = blockIdx.z;
  const float* src = P.src[z];
  short* dst = P.dst[z];
  const int tid = threadIdx.x;
#pragma unroll
  for (int i = 0; i < 16; i++) {
    int kk = i * 4 + (tid >> 6);
    int nn = tid & 63;
    t[kk][nn] = src[(kt * 64 + kk) * 512 + nt * 64 + nn];
  }
  __syncthreads();
#pragma unroll
  for (int i = 0; i < 2; i++) {
    int seg = i * 256 + tid;
    int nn = seg >> 3, k8 = seg & 7;
    short tmp[8];
#pragma unroll
    for (int k = 0; k < 8; k++) tmp[k] = f2bf(t[k8 * 8 + k][nn]);
    *(uint4*)&dst[(nt * 64 + nn) * 512 + kt * 64 + k8 * 8] = *(const uint4*)tmp;
  }
}

__global__ void bsum_k(const float* a, const float* b, const float* c, float* o) {
  int i = blockIdx.x * 256 + threadIdx.x;
  if (i < 512) o[i] = a[i] + b[i] + c[i];
}

// ---------- 256x256 8-phase GEMM: D = A(MxK) * B(NxK)^T, bf16 in ----------
// LDS: 2 buffers x {ALO, AHI, BLO, BHI}, each K-half = 256 rows x 32 k x 2B = 16 KB.
// XOR swizzle p ^= ((p>>8)&3)<<4 within each 1 KiB subtile (involution):
//   read side: kl ^= r4>>2 (per-thread constant); stage side: global chunk ^= (tid>>4)&3,
//   LDS dest stays linear (global_load_lds requirement). Bank-uniform b128 reads.
// Phases per K-tile t: P0(kh0,mq0) P1(kh0,mq1) P2(kh1,mq0) P3(kh1,mq1).
// Stage stream (2 gload_lds/thread/phase): P0:AHI(t+1) P1:BHI(t+1) P2:ALO(t+2) P3:BLO(t+2).
// Queue at P0 entry: [ALO(t),BLO(t),AHI(t),BHI(t),ALO(t+1),BLO(t+1)] = 12 -> vmcnt(8).
// Queue at P2 entry: [AHI(t),BHI(t),ALO(t+1),BLO(t+1),AHI(t+1),BHI(t+1)] = 12 -> vmcnt(8).
// Tail: peel NT-2 (stages hi only, 8/8) and NT-1 (no stages, 4/0).
// MODE 0: D bf16 [M][ldd].  MODE 1: D f32 out (B,C,THW) = v + bsum[c].  MODE 2: D += v.
#define LOADB(b, kh)                                                           \
  do {                                                                         \
    _Pragma("unroll") for (int ni = 0; ni < 4; ++ni) bfr[ni] =                 \
        *(const bf16x8*)(smem + ((b) * 4 + 2 + (kh)) * 16384 + boff +          \
                         ni * 1024);                                           \
  } while (0)

#define LOADA(b, kh, mq)                                                       \
  do {                                                                         \
    _Pragma("unroll") for (int mi = 0; mi < 4; ++mi) af[mi] =                  \
        *(const bf16x8*)(smem + ((b) * 4 + (kh)) * 16384 + aoff +              \
                         ((mq) * 4 + mi) * 1024);                              \
  } while (0)

#define MFMA16(mq)                                                             \
  do {                                                                         \
    __builtin_amdgcn_s_setprio(1);                                             \
    _Pragma("unroll") for (int mi = 0; mi < 4; ++mi)                           \
        _Pragma("unroll") for (int ni = 0; ni < 4; ++ni) acc[(mq) * 4 + mi]    \
            [ni] = __builtin_amdgcn_mfma_f32_16x16x32_bf16(                    \
                af[mi], bfr[ni], acc[(mq) * 4 + mi][ni], 0, 0, 0);             \
    __builtin_amdgcn_s_setprio(0);                                             \
    GFENCE;                                                                    \
  } while (0)

#define TILE(b, W0, W2, S0, S1, S2, S3)                                        \
  do {                                                                         \
    asm volatile("s_waitcnt vmcnt(" W0 ")" ::: "memory");                      \
    __builtin_amdgcn_s_barrier();                                              \
    GFENCE;                                                                    \
    LOADB(b, 0);                                                               \
    LOADA(b, 0, 0);                                                            \
    S0;                                                                        \
    MFMA16(0);                                                                 \
    __builtin_amdgcn_s_barrier();                                              \
    GFENCE;                                                                    \
    LOADA(b, 0, 1);                                                            \
    S1;                                                                        \
    MFMA16(1);                                                                 \
    asm volatile("s_waitcnt vmcnt(" W2 ")" ::: "memory");                      \
    __builtin_amdgcn_s_barrier();                                              \
    GFENCE;                                                                    \
    LOADB(b, 1);                                                               \
    LOADA(b, 1, 0);                                                            \
    S2;                                                                        \
    MFMA16(0);                                                                 \
    __builtin_amdgcn_s_barrier();                                              \
    GFENCE;                                                                    \
    LOADA(b, 1, 1);                                                            \
    S3;                                                                        \
    MFMA16(1);                                                                 \
  } while (0)

template <int MODE>
__global__ __launch_bounds__(512, 2) void gemm256_k(const short* __restrict__ A,
                                                    const short* __restrict__ B,
                                                    void* __restrict__ Dp, int K,
                                                    int ldd,
                                                    const float* __restrict__ bsum,
                                                    int GN) {
  extern __shared__ char smem[];
  const int tid = threadIdx.x;
  const int lane = tid & 63, wave = tid >> 6;
  const int wr = wave >> 2, wc = wave & 3;
  const int r4 = lane & 15, kl = lane >> 4;

  // bijective XCD swizzle (gridDim.x % 8 == 0 for all our grids)
  int bid = blockIdx.x;
  const int cpx = gridDim.x >> 3;
  bid = (bid & 7) * cpx + (bid >> 3);
  int bm, bn;
  if constexpr (MODE == 0) {
    bn = bid % GN;
    bm = bid / GN;
  } else {
    bm = bid & 1;
    bn = bid >> 1;
  }

  const int NT = K >> 6;

  // staging: per thread row/chunk; chunk pre-swizzled so linear LDS dest +
  // swizzled read are consistent (involution).
  const int srow = tid >> 2;                       // 0..127 (instr i adds 128)
  const int schk = (tid & 3) ^ ((tid >> 4) & 3);   // swizzled 16B chunk
  const short* gA0 = A + (size_t)(bm * 256 + srow) * K + schk * 8;
  const short* gB0 = B + (size_t)(bn * 256 + srow) * K + schk * 8;

  auto stage = [&](int tt, int x) {  // x: 0 ALO, 1 AHI, 2 BLO, 3 BHI
    const short* g = (x < 2) ? gA0 : gB0;
    const size_t koff = (size_t)tt * 64 + (x & 1) * 32;
    char* ldst = smem + (((tt & 1) * 4 + x) * 16384) + wave * 1024;
#pragma unroll
    for (int i = 0; i < 2; ++i)
      gload_lds16(g + (size_t)i * 128 * K + koff, ldst + i * 8192);
  };

  // fragment read offsets (swizzled: kl ^= r4>>2 within the 1 KiB subtile)
  const int kls = kl ^ (r4 >> 2);
  const int aoff = wr * 8192 + r4 * 64 + kls * 16;
  const int boff = wc * 4096 + r4 * 64 + kls * 16;

  f32x4 acc[8][4];
#pragma unroll
  for (int i = 0; i < 8; ++i)
#pragma unroll
    for (int j = 0; j < 4; ++j) acc[i][j] = (f32x4){0.f, 0.f, 0.f, 0.f};
  bf16x8 af[4], bfr[4];

  // prologue: ALO0 BLO0 AHI0 BHI0 ALO1 BLO1  (12 loads/thread in flight)
  stage(0, 0);
  stage(0, 2);
  stage(0, 1);
  stage(0, 3);
  stage(1, 0);
  stage(1, 2);

  int t = 0;
  for (; t < NT - 2; ++t) {
    const int b = t & 1;
    TILE(b, "8", "8", stage(t + 1, 1), stage(t + 1, 3), stage(t + 2, 0),
         stage(t + 2, 2));
  }
  {
    const int b = t & 1;  // t == NT-2: stage hi of last tile only
    TILE(b, "8", "8", stage(t + 1, 1), stage(t + 1, 3), (void)0, (void)0);
    ++t;
  }
  {
    const int b = t & 1;  // t == NT-1: nothing left to stage
    TILE(b, "4", "0", (void)0, (void)0, (void)0, (void)0);
  }

  // ---- epilogue
  const int m0 = wr * 128 + kl * 4;
  const int n0 = wc * 64 + r4;
  if (MODE == 0) {
    short* D = (short*)Dp;
#pragma unroll
    for (int mi = 0; mi < 8; ++mi)
#pragma unroll
      for (int ni = 0; ni < 4; ++ni)
#pragma unroll
        for (int r = 0; r < 4; ++r) {
          int row = bm * 256 + m0 + mi * 16 + r;
          int col = bn * 256 + n0 + ni * 16;
          D[(size_t)row * ldd + col] = f2bf(acc[mi][ni][r]);
        }
  } else {
    float* D = (float*)Dp + (size_t)((bn * 256) >> 14) * 8388608;
#pragma unroll
    for (int mi = 0; mi < 8; ++mi)
#pragma unroll
      for (int ni = 0; ni < 4; ++ni)
#pragma unroll
        for (int r = 0; r < 4; ++r) {
          int c = bm * 256 + m0 + mi * 16 + r;          // channel (M dim)
          int n = (bn * 256 + n0 + ni * 16) & 16383;    // spatial within batch
          if (MODE == 1)
            D[(size_t)c * 16384 + n] = acc[mi][ni][r] + bsum[c];
          else
            D[(size_t)c * 16384 + n] += acc[mi][ni][r];
        }
  }
}

// ---------- axial attention: one block per (sequence, head) ----------
// qkv: [n][1536] bf16 (Q|K|V each 512); o: [n][512] bf16
template <int L>
__global__ __launch_bounds__(256) void attn_k(const short* __restrict__ qkv,
                                              short* __restrict__ o, int Adiv, int Bmul,
                                              int Cmul, int stride) {
  constexpr int R = 256 / L;          // threads per row
  constexpr int SPT = (L * L) / 256;  // scores per thread
  constexpr int OPT = 64 / R;         // outputs per thread
  __shared__ short Ks[L][72];
  __shared__ short Vs[L][72];
  __shared__ short Qs[L][72];
  __shared__ float att[L][L + 1];
  const int tid = threadIdx.x;
  const int blk = blockIdx.x;
  const int s = blk >> 3, head = blk & 7;
  const int base = (s / Adiv) * Bmul + (s % Adiv) * Cmul;

  for (int idx = tid; idx < L * 8 * 3; idx += 256) {
    int part = idx / (L * 8);
    int rem = idx - part * (L * 8);
    int row = rem >> 3, seg = rem & 7;
    int n = base + row * stride;
    uint4 v = *(const uint4*)&qkv[(size_t)n * 1536 + part * 512 + head * 64 + seg * 8];
    short* dst = (part == 0 ? &Qs[row][0] : part == 1 ? &Ks[row][0] : &Vs[row][0]);
    *(uint4*)(dst + seg * 8) = v;
  }
  __syncthreads();

  const int l = tid / R, r = tid % R;
  float q[64];
#pragma unroll
  for (int w = 0; w < 8; w++) {
    uint4 u = *(const uint4*)&Qs[l][w * 8];
    uint32_t arr[4] = {u.x, u.y, u.z, u.w};
#pragma unroll
    for (int p = 0; p < 4; p++) {
      q[w * 8 + p * 2] = __builtin_bit_cast(float, arr[p] << 16);
      q[w * 8 + p * 2 + 1] = __builtin_bit_cast(float, arr[p] & 0xffff0000u);
    }
  }
  float sc[SPT];
#pragma unroll
  for (int jj = 0; jj < SPT; jj++) {
    int j = jj * R + r;
    float a0 = 0.f;
#pragma unroll
    for (int w = 0; w < 8; w++) {
      uint4 u = *(const uint4*)&Ks[j][w * 8];
      uint32_t arr[4] = {u.x, u.y, u.z, u.w};
#pragma unroll
      for (int p = 0; p < 4; p++) {
        a0 += q[w * 8 + p * 2] * __builtin_bit_cast(float, arr[p] << 16);
        a0 += q[w * 8 + p * 2 + 1] * __builtin_bit_cast(float, arr[p] & 0xffff0000u);
      }
    }
    sc[jj] = a0 * 0.125f;  // 1/sqrt(64)
  }
  float mx = sc[0];
#pragma unroll
  for (int jj = 1; jj < SPT; jj++) mx = fmaxf(mx, sc[jj]);
#pragma unroll
  for (int d = 1; d < R; d <<= 1) mx = fmaxf(mx, __shfl_xor(mx, d));
  float p_[SPT];
  float sum = 0.f;
#pragma unroll
  for (int jj = 0; jj < SPT; jj++) {
    p_[jj] = __expf(sc[jj] - mx);
    sum += p_[jj];
  }
#pragma unroll
  for (int d = 1; d < R; d <<= 1) sum += __shfl_xor(sum, d);
  float inv = 1.0f / sum;
#pragma unroll
  for (int jj = 0; jj < SPT; jj++) att[l][jj * R + r] = p_[jj] * inv;
  __syncthreads();

  float oa[OPT] = {};
#pragma unroll 4
  for (int j = 0; j < L; j++) {
    float a = att[l][j];
    if constexpr (OPT == 8) {
      uint4 u = *(const uint4*)&Vs[j][r * 8];
      uint32_t arr[4] = {u.x, u.y, u.z, u.w};
#pragma unroll
      for (int p = 0; p < 4; p++) {
        oa[p * 2] += a * __builtin_bit_cast(float, arr[p] << 16);
        oa[p * 2 + 1] += a * __builtin_bit_cast(float, arr[p] & 0xffff0000u);
      }
    } else {
      uint2 u = *(const uint2*)&Vs[j][r * 4];
      uint32_t arr[2] = {u.x, u.y};
#pragma unroll
      for (int p = 0; p < 2; p++) {
        oa[p * 2] += a * __builtin_bit_cast(float, arr[p] << 16);
        oa[p * 2 + 1] += a * __builtin_bit_cast(float, arr[p] & 0xffff0000u);
      }
    }
  }
  short tmp[OPT];
#pragma unroll
  for (int i = 0; i < OPT; i++) tmp[i] = f2bf(oa[i]);
  int n = base + l * stride;
  if constexpr (OPT == 8)
    *(uint4*)&o[(size_t)n * 512 + head * 64 + r * 8] = *(const uint4*)tmp;
  else
    *(uint2*)&o[(size_t)n * 512 + head * 64 + r * 4] = *(const uint2*)tmp;
}

// ---------- launch ----------
extern "C" void kernel_launch(void* const* d_in, const int* in_sizes, int n_in,
                              void* d_out, int out_size, void* d_ws, size_t ws_size,
                              hipStream_t stream) {
  const float* x = (const float*)d_in[0];
  const float* wq[3];
  const float* wk[3];
  const float* wv[3];
  const float* fc[3];
  const float* fb[3];
  for (int a = 0; a < 3; a++) {
    wq[a] = (const float*)d_in[1 + a * 5];
    wk[a] = (const float*)d_in[2 + a * 5];
    wv[a] = (const float*)d_in[3 + a * 5];
    fc[a] = (const float*)d_in[4 + a * 5];
    fb[a] = (const float*)d_in[5 + a * 5];
  }
  char* ws = (char*)d_ws;
  short* xb = (short*)(ws);                      //  67,108,864 B
  short* qkv = (short*)(ws + 67108864);          // 201,326,592 B
  short* ob = (short*)(ws + 268435456);          //  67,108,864 B
  short* wqkvt = (short*)(ws + 335544320);       //   4,718,592 B (3 x 1536x512)
  short* fct = (short*)(ws + 340262912);         //   1,572,864 B (3 x 512x512)
  float* bsum = (float*)(ws + 341835776);        //       2,048 B
  float* out = (float*)d_out;

  // allow 128 KiB dynamic LDS (host-side, capture-safe)
  (void)hipFuncSetAttribute((const void*)&gemm256_k<0>,
                            hipFuncAttributeMaxDynamicSharedMemorySize, 131072);
  (void)hipFuncSetAttribute((const void*)&gemm256_k<1>,
                            hipFuncAttributeMaxDynamicSharedMemorySize, 131072);
  (void)hipFuncSetAttribute((const void*)&gemm256_k<2>,
                            hipFuncAttributeMaxDynamicSharedMemorySize, 131072);

  WPtrs P;
  for (int a = 0; a < 3; a++) {
    P.src[a * 4 + 0] = wq[a];
    P.src[a * 4 + 1] = wk[a];
    P.src[a * 4 + 2] = wv[a];
    P.src[a * 4 + 3] = fc[a];
    P.dst[a * 4 + 0] = wqkvt + (size_t)a * 1536 * 512;
    P.dst[a * 4 + 1] = wqkvt + (size_t)a * 1536 * 512 + 512 * 512;
    P.dst[a * 4 + 2] = wqkvt + (size_t)a * 1536 * 512 + 2 * 512 * 512;
    P.dst[a * 4 + 3] = fct + (size_t)a * 512 * 512;
  }
  transpose_w_k<<<dim3(8, 8, 12), 256, 0, stream>>>(P);
  bsum_k<<<dim3(2), 256, 0, stream>>>(fb[0], fb[1], fb[2], bsum);
  transpose_x_k<<<dim3(256, 8, 4), 256, 0, stream>>>(x, xb);

  // per-axis attention geometry: base = (s/Adiv)*Bmul + (s%Adiv)*Cmul, rows step `stride`
  const int Ad[3] = {1, 32, 1024};
  const int Bm_[3] = {32, 1024, 16384};
  const int Cm[3] = {0, 1, 1};
  const int St[3] = {1, 32, 1024};
  const int Ls[3] = {32, 32, 16};

  for (int a = 0; a < 3; a++) {
    // QKV: M=65536 (256 bm tiles), N=1536 (6 bn tiles), K=512
    gemm256_k<0><<<dim3(1536), 512, 131072, stream>>>(
        xb, wqkvt + (size_t)a * 1536 * 512, (void*)qkv, 512, 1536, nullptr, 6);
    if (Ls[a] == 32)
      attn_k<32><<<dim3(2048 * 8), 256, 0, stream>>>(qkv, ob, Ad[a], Bm_[a], Cm[a], St[a]);
    else
      attn_k<16><<<dim3(4096 * 8), 256, 0, stream>>>(qkv, ob, Ad[a], Bm_[a], Cm[a], St[a]);
    // fc: M=512 (2 bm tiles), N=65536 (256 bn tiles), K=512
    if (a == 0)
      gemm256_k<1><<<dim3(512), 512, 131072, stream>>>(
          fct + (size_t)a * 512 * 512, ob, (void*)out, 512, 0, bsum, 0);
    else
      gemm256_k<2><<<dim3(512), 512, 131072, stream>>>(
          fct + (size_t)a * 512 * 512, ob, (void*)out, 512, 0, bsum, 0);
  }
}

// Round 4
// 830.996 us; speedup vs baseline: 1.3351x; 1.1324x over previous
//
#include <hip/hip_runtime.h>
#include <stdint.h>

// ---------- types / helpers ----------
typedef __attribute__((ext_vector_type(8))) short bf16x8;   // 8 bf16 in 4 VGPRs
typedef __attribute__((ext_vector_type(4))) float f32x4;

static __device__ __forceinline__ short f2bf(float f) {
  uint32_t u = __builtin_bit_cast(uint32_t, f);
  u += 0x7fffu + ((u >> 16) & 1u);          // round-to-nearest-even
  return (short)(u >> 16);
}

static __device__ __forceinline__ void gload_lds16(const void* g, void* l) {
  __builtin_amdgcn_global_load_lds((const __attribute__((address_space(1))) void*)g,
                                   (__attribute__((address_space(3))) void*)l, 16, 0, 0);
}

#define GFENCE asm volatile("" ::: "memory")

// ---------- x transpose: (B,C,T,H,W) f32 -> xb[n][c] bf16, n = b*16384 + p ----------
__global__ __launch_bounds__(256) void transpose_x_k(const float* __restrict__ x,
                                                     short* __restrict__ xb) {
  __shared__ float t[64][65];
  const int pt = blockIdx.x, ct = blockIdx.y, b = blockIdx.z;
  const int tid = threadIdx.x;
#pragma unroll
  for (int i = 0; i < 16; i++) {
    int cc = i * 4 + (tid >> 6);
    int pp = tid & 63;
    t[cc][pp] = x[(size_t)(b * 512 + ct * 64 + cc) * 16384 + pt * 64 + pp];
  }
  __syncthreads();
#pragma unroll
  for (int i = 0; i < 2; i++) {
    int seg = i * 256 + tid;
    int pw = seg >> 3, c8 = seg & 7;
    short tmp[8];
#pragma unroll
    for (int k = 0; k < 8; k++) tmp[k] = f2bf(t[c8 * 8 + k][pw]);
    *(uint4*)&xb[(size_t)(b * 16384 + pt * 64 + pw) * 512 + ct * 64 + c8 * 8] =
        *(const uint4*)tmp;
  }
}

// ---------- weight transpose: 12x (512x512 f32 [k][n]) -> bf16 [n][k], per-dst ld ----------
struct WPtrs {
  const float* src[12];
  short* dst[12];
  int ld[12];
};

__global__ __launch_bounds__(256) void transpose_w_k(WPtrs P) {
  __shared__ float t[64][65];
  const int kt = blockIdx.x, nt = blockIdx.y, z = blockIdx.z;
  const float* src = P.src[z];
  short* dst = P.dst[z];
  const int ld = P.ld[z];
  const int tid = threadIdx.x;
#pragma unroll
  for (int i = 0; i < 16; i++) {
    int kk = i * 4 + (tid >> 6);
    int nn = tid & 63;
    t[kk][nn] = src[(kt * 64 + kk) * 512 + nt * 64 + nn];
  }
  __syncthreads();
#pragma unroll
  for (int i = 0; i < 2; i++) {
    int seg = i * 256 + tid;
    int nn = seg >> 3, k8 = seg & 7;
    short tmp[8];
#pragma unroll
    for (int k = 0; k < 8; k++) tmp[k] = f2bf(t[k8 * 8 + k][nn]);
    *(uint4*)&dst[(size_t)(nt * 64 + nn) * ld + kt * 64 + k8 * 8] = *(const uint4*)tmp;
  }
}

__global__ void bsum_k(const float* a, const float* b, const float* c, float* o) {
  int i = blockIdx.x * 256 + threadIdx.x;
  if (i < 512) o[i] = a[i] + b[i] + c[i];
}

// ---------- 256x256 8-phase GEMM: D = A(MxK, lda) * B(NxK, ldb)^T, bf16 in ----------
// (schedule identical to the round-3 proven version; lda/ldb parametrized)
// LDS: 2 buffers x {ALO, AHI, BLO, BHI}, each K-half = 256 rows x 32 k x 2B = 16 KB.
// XOR swizzle within 1 KiB subtile: read kl ^= r4>>2; stage global chunk ^= (tid>>4)&3.
// Phases per K-tile t: P0(kh0,mq0) P1(kh0,mq1) P2(kh1,mq0) P3(kh1,mq1).
// Stage stream: P0:AHI(t+1) P1:BHI(t+1) P2:ALO(t+2) P3:BLO(t+2).
// Waits: vmcnt(8) @P0 and @P2 (12 outstanding, retire current tile's halves).
// Tail: peel NT-2 (hi stages only, 8/8) and NT-1 (no stages, 4/0).
// MODE 0: D bf16 [M][ldd].  MODE 1: D f32 out (B,C,THW) = v + bsum[c].  MODE 2: D += v.
#define LOADB(b, kh)                                                           \
  do {                                                                         \
    _Pragma("unroll") for (int ni = 0; ni < 4; ++ni) bfr[ni] =                 \
        *(const bf16x8*)(smem + ((b) * 4 + 2 + (kh)) * 16384 + boff +          \
                         ni * 1024);                                           \
  } while (0)

#define LOADA(b, kh, mq)                                                       \
  do {                                                                         \
    _Pragma("unroll") for (int mi = 0; mi < 4; ++mi) af[mi] =                  \
        *(const bf16x8*)(smem + ((b) * 4 + (kh)) * 16384 + aoff +              \
                         ((mq) * 4 + mi) * 1024);                              \
  } while (0)

#define MFMA16(mq)                                                             \
  do {                                                                         \
    __builtin_amdgcn_s_setprio(1);                                             \
    _Pragma("unroll") for (int mi = 0; mi < 4; ++mi)                           \
        _Pragma("unroll") for (int ni = 0; ni < 4; ++ni) acc[(mq) * 4 + mi]    \
            [ni] = __builtin_amdgcn_mfma_f32_16x16x32_bf16(                    \
                af[mi], bfr[ni], acc[(mq) * 4 + mi][ni], 0, 0, 0);             \
    __builtin_amdgcn_s_setprio(0);                                             \
    GFENCE;                                                                    \
  } while (0)

#define TILE(b, W0, W2, S0, S1, S2, S3)                                        \
  do {                                                                         \
    asm volatile("s_waitcnt vmcnt(" W0 ")" ::: "memory");                      \
    __builtin_amdgcn_s_barrier();                                              \
    GFENCE;                                                                    \
    LOADB(b, 0);                                                               \
    LOADA(b, 0, 0);                                                            \
    S0;                                                                        \
    MFMA16(0);                                                                 \
    __builtin_amdgcn_s_barrier();                                              \
    GFENCE;                                                                    \
    LOADA(b, 0, 1);                                                            \
    S1;                                                                        \
    MFMA16(1);                                                                 \
    asm volatile("s_waitcnt vmcnt(" W2 ")" ::: "memory");                      \
    __builtin_amdgcn_s_barrier();                                              \
    GFENCE;                                                                    \
    LOADB(b, 1);                                                               \
    LOADA(b, 1, 0);                                                            \
    S2;                                                                        \
    MFMA16(0);                                                                 \
    __builtin_amdgcn_s_barrier();                                              \
    GFENCE;                                                                    \
    LOADA(b, 1, 1);                                                            \
    S3;                                                                        \
    MFMA16(1);                                                                 \
  } while (0)

template <int MODE>
__global__ __launch_bounds__(512, 2) void gemm256_k(const short* __restrict__ A,
                                                    int lda,
                                                    const short* __restrict__ B,
                                                    int ldb, void* __restrict__ Dp,
                                                    int K, int ldd,
                                                    const float* __restrict__ bsum,
                                                    int GN) {
  extern __shared__ char smem[];
  const int tid = threadIdx.x;
  const int lane = tid & 63, wave = tid >> 6;
  const int wr = wave >> 2, wc = wave & 3;
  const int r4 = lane & 15, kl = lane >> 4;

  // bijective XCD swizzle (gridDim.x % 8 == 0 for all our grids)
  int bid = blockIdx.x;
  const int cpx = gridDim.x >> 3;
  bid = (bid & 7) * cpx + (bid >> 3);
  int bm, bn;
  if constexpr (MODE == 0) {
    bn = bid % GN;
    bm = bid / GN;
  } else {
    bm = bid & 1;
    bn = bid >> 1;
  }

  const int NT = K >> 6;

  // staging: per thread row/chunk; chunk pre-swizzled (involution) so linear
  // LDS dest + swizzled read are consistent.
  const int srow = tid >> 2;                       // 0..127 (instr i adds 128)
  const int schk = (tid & 3) ^ ((tid >> 4) & 3);   // swizzled 16B chunk
  const short* gA0 = A + (size_t)(bm * 256 + srow) * lda + schk * 8;
  const short* gB0 = B + (size_t)(bn * 256 + srow) * ldb + schk * 8;

  auto stage = [&](int tt, int x) {  // x: 0 ALO, 1 AHI, 2 BLO, 3 BHI
    const short* g = (x < 2) ? gA0 : gB0;
    const size_t rstep = (size_t)128 * ((x < 2) ? lda : ldb);
    const size_t koff = (size_t)tt * 64 + (x & 1) * 32;
    char* ldst = smem + (((tt & 1) * 4 + x) * 16384) + wave * 1024;
#pragma unroll
    for (int i = 0; i < 2; ++i)
      gload_lds16(g + i * rstep + koff, ldst + i * 8192);
  };

  // fragment read offsets (swizzled: kl ^= r4>>2 within the 1 KiB subtile)
  const int kls = kl ^ (r4 >> 2);
  const int aoff = wr * 8192 + r4 * 64 + kls * 16;
  const int boff = wc * 4096 + r4 * 64 + kls * 16;

  f32x4 acc[8][4];
#pragma unroll
  for (int i = 0; i < 8; ++i)
#pragma unroll
    for (int j = 0; j < 4; ++j) acc[i][j] = (f32x4){0.f, 0.f, 0.f, 0.f};
  bf16x8 af[4], bfr[4];

  // prologue: ALO0 BLO0 AHI0 BHI0 ALO1 BLO1  (12 loads/thread in flight)
  stage(0, 0);
  stage(0, 2);
  stage(0, 1);
  stage(0, 3);
  stage(1, 0);
  stage(1, 2);

  int t = 0;
  for (; t < NT - 2; ++t) {
    const int b = t & 1;
    TILE(b, "8", "8", stage(t + 1, 1), stage(t + 1, 3), stage(t + 2, 0),
         stage(t + 2, 2));
  }
  {
    const int b = t & 1;  // t == NT-2: stage hi of last tile only
    TILE(b, "8", "8", stage(t + 1, 1), stage(t + 1, 3), (void)0, (void)0);
    ++t;
  }
  {
    const int b = t & 1;  // t == NT-1: nothing left to stage
    TILE(b, "4", "0", (void)0, (void)0, (void)0, (void)0);
  }

  // ---- epilogue
  const int m0 = wr * 128 + kl * 4;
  const int n0 = wc * 64 + r4;
  if (MODE == 0) {
    short* D = (short*)Dp;
#pragma unroll
    for (int mi = 0; mi < 8; ++mi)
#pragma unroll
      for (int ni = 0; ni < 4; ++ni)
#pragma unroll
        for (int r = 0; r < 4; ++r) {
          int row = bm * 256 + m0 + mi * 16 + r;
          int col = bn * 256 + n0 + ni * 16;
          D[(size_t)row * ldd + col] = f2bf(acc[mi][ni][r]);
        }
  } else {
    float* D = (float*)Dp + (size_t)((bn * 256) >> 14) * 8388608;
#pragma unroll
    for (int mi = 0; mi < 8; ++mi)
#pragma unroll
      for (int ni = 0; ni < 4; ++ni)
#pragma unroll
        for (int r = 0; r < 4; ++r) {
          int c = bm * 256 + m0 + mi * 16 + r;          // channel (M dim)
          int n = (bn * 256 + n0 + ni * 16) & 16383;    // spatial within batch
          if (MODE == 1)
            D[(size_t)c * 16384 + n] = acc[mi][ni][r] + bsum[c];
          else
            D[(size_t)c * 16384 + n] += acc[mi][ni][r];
        }
  }
}

// ---------- axial attention: one block per (sequence, head) ----------
// qkv: [n][1536] bf16 (Q|K|V each 512); o: [n][ostride] bf16 at column obase
template <int L>
__global__ __launch_bounds__(256) void attn_k(const short* __restrict__ qkv,
                                              short* __restrict__ o, int Adiv, int Bmul,
                                              int Cmul, int stride, int obase,
                                              int ostride) {
  constexpr int R = 256 / L;          // threads per row
  constexpr int SPT = (L * L) / 256;  // scores per thread
  constexpr int OPT = 64 / R;         // outputs per thread
  __shared__ short Ks[L][72];
  __shared__ short Vs[L][72];
  __shared__ short Qs[L][72];
  __shared__ float att[L][L + 1];
  const int tid = threadIdx.x;
  const int blk = blockIdx.x;
  const int s = blk >> 3, head = blk & 7;
  const int base = (s / Adiv) * Bmul + (s % Adiv) * Cmul;

  for (int idx = tid; idx < L * 8 * 3; idx += 256) {
    int part = idx / (L * 8);
    int rem = idx - part * (L * 8);
    int row = rem >> 3, seg = rem & 7;
    int n = base + row * stride;
    uint4 v = *(const uint4*)&qkv[(size_t)n * 1536 + part * 512 + head * 64 + seg * 8];
    short* dst = (part == 0 ? &Qs[row][0] : part == 1 ? &Ks[row][0] : &Vs[row][0]);
    *(uint4*)(dst + seg * 8) = v;
  }
  __syncthreads();

  const int l = tid / R, r = tid % R;
  float q[64];
#pragma unroll
  for (int w = 0; w < 8; w++) {
    uint4 u = *(const uint4*)&Qs[l][w * 8];
    uint32_t arr[4] = {u.x, u.y, u.z, u.w};
#pragma unroll
    for (int p = 0; p < 4; p++) {
      q[w * 8 + p * 2] = __builtin_bit_cast(float, arr[p] << 16);
      q[w * 8 + p * 2 + 1] = __builtin_bit_cast(float, arr[p] & 0xffff0000u);
    }
  }
  float sc[SPT];
#pragma unroll
  for (int jj = 0; jj < SPT; jj++) {
    int j = jj * R + r;
    float a0 = 0.f;
#pragma unroll
    for (int w = 0; w < 8; w++) {
      uint4 u = *(const uint4*)&Ks[j][w * 8];
      uint32_t arr[4] = {u.x, u.y, u.z, u.w};
#pragma unroll
      for (int p = 0; p < 4; p++) {
        a0 += q[w * 8 + p * 2] * __builtin_bit_cast(float, arr[p] << 16);
        a0 += q[w * 8 + p * 2 + 1] * __builtin_bit_cast(float, arr[p] & 0xffff0000u);
      }
    }
    sc[jj] = a0 * 0.125f;  // 1/sqrt(64)
  }
  float mx = sc[0];
#pragma unroll
  for (int jj = 1; jj < SPT; jj++) mx = fmaxf(mx, sc[jj]);
#pragma unroll
  for (int d = 1; d < R; d <<= 1) mx = fmaxf(mx, __shfl_xor(mx, d));
  float p_[SPT];
  float sum = 0.f;
#pragma unroll
  for (int jj = 0; jj < SPT; jj++) {
    p_[jj] = __expf(sc[jj] - mx);
    sum += p_[jj];
  }
#pragma unroll
  for (int d = 1; d < R; d <<= 1) sum += __shfl_xor(sum, d);
  float inv = 1.0f / sum;
#pragma unroll
  for (int jj = 0; jj < SPT; jj++) att[l][jj * R + r] = p_[jj] * inv;
  __syncthreads();

  float oa[OPT] = {};
#pragma unroll 4
  for (int j = 0; j < L; j++) {
    float a = att[l][j];
    if constexpr (OPT == 8) {
      uint4 u = *(const uint4*)&Vs[j][r * 8];
      uint32_t arr[4] = {u.x, u.y, u.z, u.w};
#pragma unroll
      for (int p = 0; p < 4; p++) {
        oa[p * 2] += a * __builtin_bit_cast(float, arr[p] << 16);
        oa[p * 2 + 1] += a * __builtin_bit_cast(float, arr[p] & 0xffff0000u);
      }
    } else {
      uint2 u = *(const uint2*)&Vs[j][r * 4];
      uint32_t arr[2] = {u.x, u.y};
#pragma unroll
      for (int p = 0; p < 2; p++) {
        oa[p * 2] += a * __builtin_bit_cast(float, arr[p] << 16);
        oa[p * 2 + 1] += a * __builtin_bit_cast(float, arr[p] & 0xffff0000u);
      }
    }
  }
  short tmp[OPT];
#pragma unroll
  for (int i = 0; i < OPT; i++) tmp[i] = f2bf(oa[i]);
  int n = base + l * stride;
  if constexpr (OPT == 8)
    *(uint4*)&o[(size_t)n * ostride + obase + head * 64 + r * 8] = *(const uint4*)tmp;
  else
    *(uint2*)&o[(size_t)n * ostride + obase + head * 64 + r * 4] = *(const uint2*)tmp;
}

// ---------- launch ----------
extern "C" void kernel_launch(void* const* d_in, const int* in_sizes, int n_in,
                              void* d_out, int out_size, void* d_ws, size_t ws_size,
                              hipStream_t stream) {
  const float* x = (const float*)d_in[0];
  const float* wq[3];
  const float* wk[3];
  const float* wv[3];
  const float* fc[3];
  const float* fb[3];
  for (int a = 0; a < 3; a++) {
    wq[a] = (const float*)d_in[1 + a * 5];
    wk[a] = (const float*)d_in[2 + a * 5];
    wv[a] = (const float*)d_in[3 + a * 5];
    fc[a] = (const float*)d_in[4 + a * 5];
    fb[a] = (const float*)d_in[5 + a * 5];
  }
  char* ws = (char*)d_ws;
  short* xb = (short*)(ws);                      //  67,108,864 B
  short* qkv = (short*)(ws + 67108864);          // 201,326,592 B
  short* wqkvt = (short*)(ws + 268435456);       //   4,718,592 B (3 x 1536x512)
  short* fctA = (short*)(ws + 273154048);        //   1,572,864 B (512 x 1536)
  float* bsum = (float*)(ws + 274726912);        //       2,048 B
  short* ob = (short*)(ws + 274728960);          // 67 MB (fallback) / 201 MB (fused)
  float* out = (float*)d_out;

  // fused fc path needs ob_all = 65536x1536 bf16 -> total 476,055,552 B
  const bool fused = ws_size >= 476055552ull;

  // allow 128 KiB dynamic LDS (host-side, capture-safe)
  (void)hipFuncSetAttribute((const void*)&gemm256_k<0>,
                            hipFuncAttributeMaxDynamicSharedMemorySize, 131072);
  (void)hipFuncSetAttribute((const void*)&gemm256_k<1>,
                            hipFuncAttributeMaxDynamicSharedMemorySize, 131072);
  (void)hipFuncSetAttribute((const void*)&gemm256_k<2>,
                            hipFuncAttributeMaxDynamicSharedMemorySize, 131072);

  WPtrs P;
  for (int a = 0; a < 3; a++) {
    P.src[a * 4 + 0] = wq[a];
    P.src[a * 4 + 1] = wk[a];
    P.src[a * 4 + 2] = wv[a];
    P.src[a * 4 + 3] = fc[a];
    P.dst[a * 4 + 0] = wqkvt + (size_t)a * 1536 * 512;
    P.dst[a * 4 + 1] = wqkvt + (size_t)a * 1536 * 512 + 512 * 512;
    P.dst[a * 4 + 2] = wqkvt + (size_t)a * 1536 * 512 + 2 * 512 * 512;
    P.dst[a * 4 + 3] = fctA + a * 512;   // packed [c][a*512 + k], ld 1536
    P.ld[a * 4 + 0] = 512;
    P.ld[a * 4 + 1] = 512;
    P.ld[a * 4 + 2] = 512;
    P.ld[a * 4 + 3] = 1536;
  }
  transpose_w_k<<<dim3(8, 8, 12), 256, 0, stream>>>(P);
  bsum_k<<<dim3(2), 256, 0, stream>>>(fb[0], fb[1], fb[2], bsum);
  transpose_x_k<<<dim3(256, 8, 4), 256, 0, stream>>>(x, xb);

  // per-axis attention geometry: base = (s/Adiv)*Bmul + (s%Adiv)*Cmul, rows step `stride`
  const int Ad[3] = {1, 32, 1024};
  const int Bm_[3] = {32, 1024, 16384};
  const int Cm[3] = {0, 1, 1};
  const int St[3] = {1, 32, 1024};
  const int Ls[3] = {32, 32, 16};

  for (int a = 0; a < 3; a++) {
    // QKV: M=65536 (256 bm tiles), N=1536 (6 bn tiles), K=512
    gemm256_k<0><<<dim3(1536), 512, 131072, stream>>>(
        xb, 512, wqkvt + (size_t)a * 1536 * 512, 512, (void*)qkv, 512, 1536,
        nullptr, 6);
    const int obase = fused ? a * 512 : 0;
    const int ostr = fused ? 1536 : 512;
    if (Ls[a] == 32)
      attn_k<32><<<dim3(2048 * 8), 256, 0, stream>>>(qkv, ob, Ad[a], Bm_[a], Cm[a],
                                                     St[a], obase, ostr);
    else
      attn_k<16><<<dim3(4096 * 8), 256, 0, stream>>>(qkv, ob, Ad[a], Bm_[a], Cm[a],
                                                     St[a], obase, ostr);
    if (!fused) {
      // per-axis fc: M=512 (2 bm), N=65536 (256 bn), K=512 (A k-window a*512)
      if (a == 0)
        gemm256_k<1><<<dim3(512), 512, 131072, stream>>>(
            fctA + a * 512, 1536, ob, 512, (void*)out, 512, 0, bsum, 0);
      else
        gemm256_k<2><<<dim3(512), 512, 131072, stream>>>(
            fctA + a * 512, 1536, ob, 512, (void*)out, 512, 0, bsum, 0);
    }
  }
  if (fused) {
    // fused fc: out[c][n] = sum_a ob_all[n][a*512+k] * fctA[c][a*512+k] + bsum[c]
    // M=512 (2 bm), N=65536 (256 bn), K=1536 (NT=24), single write, no RMW
    gemm256_k<1><<<dim3(512), 512, 131072, stream>>>(
        fctA, 1536, ob, 1536, (void*)out, 1536, 0, bsum, 0);
  }
}